// Round 1
// baseline (526.375 us; speedup 1.0000x reference)
//
#include <hip/hip_runtime.h>
#include <cfloat>
#include <math.h>

// Problem constants (from reference)
#define B2   2      // true batch b
#define SS   2      // s
#define BS4  4      // bs = b*s
#define NH   8      // heads
#define DH   64     // dim_head
#define DIM  512
#define NSEQ 1024
#define AH   16     // s*heads

// ============================================================
// K1: RMSNorm over last dim + sigmoid gates (fused)
// grid = BS4*NSEQ blocks, 256 threads; one row of 512 per block
// ============================================================
__global__ __launch_bounds__(256) void k_rmsnorm_gates(
    const float* __restrict__ x, const float* __restrict__ gamma,
    const float* __restrict__ wg, const float* __restrict__ bg,
    float* __restrict__ xn, float* __restrict__ gates)
{
    int r = blockIdx.x;
    int tid = threadIdx.x;
    const float* xr = x + (size_t)r * DIM;
    float v0 = xr[tid];
    float v1 = xr[tid + 256];
    float ss = v0 * v0 + v1 * v1;
    #pragma unroll
    for (int off = 32; off > 0; off >>= 1) ss += __shfl_down(ss, off, 64);
    __shared__ float sc[4];
    __shared__ float scw[NH][4];
    if ((tid & 63) == 0) sc[tid >> 6] = ss;
    __syncthreads();
    float tot = sc[0] + sc[1] + sc[2] + sc[3];
    float rs = rsqrtf(tot * (1.0f / DIM) + 1e-5f);
    float n0 = v0 * rs * gamma[tid];
    float n1 = v1 * rs * gamma[tid + 256];
    xn[(size_t)r * DIM + tid] = n0;
    xn[(size_t)r * DIM + tid + 256] = n1;
    // gates: 8 heads, each a 512-dot of xn row with wg row
    #pragma unroll
    for (int h = 0; h < NH; ++h) {
        float p = n0 * wg[h * DIM + tid] + n1 * wg[h * DIM + tid + 256];
        #pragma unroll
        for (int off = 32; off > 0; off >>= 1) p += __shfl_down(p, off, 64);
        if ((tid & 63) == 0) scw[h][tid >> 6] = p;
    }
    __syncthreads();
    if (tid < NH) {
        float g = scw[tid][0] + scw[tid][1] + scw[tid][2] + scw[tid][3] + bg[tid];
        gates[(size_t)r * NH + tid] = 1.0f / (1.0f + __expf(-g));
    }
}

// ============================================================
// K2: QKV projection. C[4096 x 1536] = xn[4096 x 512] * wqkv^T
// 64x64 tile, BK=16, 256 threads, 4x4 per thread. Scatter epilogue
// to q/k/v laid out [bs][h][n][d]; q scaled by sqrt(64)=8.
// ============================================================
__global__ __launch_bounds__(256) void k_qkv_gemm(
    const float* __restrict__ xn, const float* __restrict__ wqkv,
    float* __restrict__ q, float* __restrict__ k, float* __restrict__ v)
{
    __shared__ float As[16][68];
    __shared__ float Bs[16][68];
    int tid = threadIdx.x;
    int tx = tid & 15, ty = tid >> 4;
    int m0 = blockIdx.y * 64;
    int n0 = blockIdx.x * 64;
    int lr = tid >> 2;
    int lc = (tid & 3) << 2;
    float acc[4][4] = {};
    for (int k0 = 0; k0 < DIM; k0 += 16) {
        float4 a = *(const float4*)(xn + (size_t)(m0 + lr) * DIM + k0 + lc);
        float4 b = *(const float4*)(wqkv + (size_t)(n0 + lr) * DIM + k0 + lc);
        As[lc + 0][lr] = a.x; As[lc + 1][lr] = a.y; As[lc + 2][lr] = a.z; As[lc + 3][lr] = a.w;
        Bs[lc + 0][lr] = b.x; Bs[lc + 1][lr] = b.y; Bs[lc + 2][lr] = b.z; Bs[lc + 3][lr] = b.w;
        __syncthreads();
        #pragma unroll
        for (int kk = 0; kk < 16; ++kk) {
            float4 av = *(const float4*)&As[kk][ty << 2];
            float4 bv = *(const float4*)&Bs[kk][tx << 2];
            float aa[4] = {av.x, av.y, av.z, av.w};
            float bb[4] = {bv.x, bv.y, bv.z, bv.w};
            #pragma unroll
            for (int e = 0; e < 4; ++e)
                #pragma unroll
                for (int f = 0; f < 4; ++f)
                    acc[e][f] = fmaf(aa[e], bb[f], acc[e][f]);
        }
        __syncthreads();
    }
    #pragma unroll
    for (int e = 0; e < 4; ++e) {
        int r = m0 + (ty << 2) + e;
        int bs = r >> 10, npos = r & 1023;
        #pragma unroll
        for (int f = 0; f < 4; ++f) {
            int ecol = n0 + (tx << 2) + f;
            int which = ecol >> 9;
            int h = (ecol >> 6) & 7;
            int d = ecol & 63;
            size_t dst = (((size_t)bs * NH + h) * NSEQ + npos) * DH + d;
            float val = acc[e][f];
            if (which == 0)      q[dst] = val * 8.0f;   // source MULTIPLIES by sqrt(dim_head)
            else if (which == 1) k[dst] = val;
            else                 v[dst] = val;
        }
    }
}

// ============================================================
// K3: sim[bh][i][j] = sum_d q[bh][i][d] * k[bh][j][d]
// batched NT GEMM, M=N=1024, K=64. grid (16,16,32)
// ============================================================
__global__ __launch_bounds__(256) void k_qk(
    const float* __restrict__ q, const float* __restrict__ k,
    float* __restrict__ sim)
{
    int bh = blockIdx.z;
    const float* A = q + (size_t)bh * NSEQ * DH;
    const float* B = k + (size_t)bh * NSEQ * DH;
    float* C = sim + (size_t)bh * NSEQ * NSEQ;
    __shared__ float As[16][68];
    __shared__ float Bs[16][68];
    int tid = threadIdx.x;
    int tx = tid & 15, ty = tid >> 4;
    int i0 = blockIdx.y * 64;
    int j0 = blockIdx.x * 64;
    int lr = tid >> 2;
    int lc = (tid & 3) << 2;
    float acc[4][4] = {};
    for (int k0 = 0; k0 < DH; k0 += 16) {
        float4 a = *(const float4*)(A + (size_t)(i0 + lr) * DH + k0 + lc);
        float4 b = *(const float4*)(B + (size_t)(j0 + lr) * DH + k0 + lc);
        As[lc + 0][lr] = a.x; As[lc + 1][lr] = a.y; As[lc + 2][lr] = a.z; As[lc + 3][lr] = a.w;
        Bs[lc + 0][lr] = b.x; Bs[lc + 1][lr] = b.y; Bs[lc + 2][lr] = b.z; Bs[lc + 3][lr] = b.w;
        __syncthreads();
        #pragma unroll
        for (int kk = 0; kk < 16; ++kk) {
            float4 av = *(const float4*)&As[kk][ty << 2];
            float4 bv = *(const float4*)&Bs[kk][tx << 2];
            float aa[4] = {av.x, av.y, av.z, av.w};
            float bb[4] = {bv.x, bv.y, bv.z, bv.w};
            #pragma unroll
            for (int e = 0; e < 4; ++e)
                #pragma unroll
                for (int f = 0; f < 4; ++f)
                    acc[e][f] = fmaf(aa[e], bb[f], acc[e][f]);
        }
        __syncthreads();
    }
    #pragma unroll
    for (int e = 0; e < 4; ++e) {
        float4 st = make_float4(acc[e][0], acc[e][1], acc[e][2], acc[e][3]);
        *(float4*)(C + (size_t)(i0 + (ty << 2) + e) * NSEQ + j0 + (tx << 2)) = st;
    }
}

// ============================================================
// K4: fused pre-talking-heads + key mask + causal + softmax +
//     post-talking-heads.
// Block per (b, i): 256 threads, each owns 4 consecutive j.
// reg[c][u]: sim row for all 16 channels; parr[o][u]: softmax probs.
// Writes post-softmax attn to d_out (output 1) and mixed attn2
// in-place over sim (block only touches its own row -> safe).
// ============================================================
__global__ __launch_bounds__(256) void k_talk_softmax(
    const float* __restrict__ sim, const int* __restrict__ mask,
    const float* __restrict__ wpre, const float* __restrict__ wpost,
    float* __restrict__ attn_out, float* __restrict__ attn2)
{
    int i = blockIdx.x;    // query position
    int b = blockIdx.y;    // true batch
    int tid = threadIdx.x;
    int j0 = tid << 2;

    float reg[16][4];
    #pragma unroll
    for (int c = 0; c < 16; ++c) {
        float4 t = *(const float4*)(sim + (((size_t)(b * 16 + c)) * NSEQ + i) * NSEQ + j0);
        reg[c][0] = t.x; reg[c][1] = t.y; reg[c][2] = t.z; reg[c][3] = t.w;
    }
    // key padding mask (per s), causal mask
    bool mb[2][4];
    #pragma unroll
    for (int s = 0; s < 2; ++s)
        #pragma unroll
        for (int u = 0; u < 4; ++u)
            mb[s][u] = (mask[(size_t)(b * 2 + s) * NSEQ + j0 + u] != 0) && ((j0 + u) <= i);

    __shared__ float red[4];
    float parr[16][4];

    #pragma unroll
    for (int o = 0; o < 16; ++o) {
        int s = o >> 3, h = o & 7;
        float val[4];
        #pragma unroll
        for (int u = 0; u < 4; ++u) {
            float a = 0.0f;
            #pragma unroll
            for (int c = 0; c < 16; ++c) a = fmaf(wpre[o * 16 + c], reg[c][u], a);
            val[u] = mb[s][u] ? a : -FLT_MAX;
        }
        float mx = fmaxf(fmaxf(val[0], val[1]), fmaxf(val[2], val[3]));
        #pragma unroll
        for (int off = 32; off > 0; off >>= 1) mx = fmaxf(mx, __shfl_down(mx, off, 64));
        __syncthreads();   // protect red[] from previous iteration's readers
        if ((tid & 63) == 0) red[tid >> 6] = mx;
        __syncthreads();
        mx = fmaxf(fmaxf(red[0], red[1]), fmaxf(red[2], red[3]));
        float ps = 0.0f;
        #pragma unroll
        for (int u = 0; u < 4; ++u) {
            float p = __expf(val[u] - mx);   // all-masked row: val==mx==-FLT_MAX -> p=1 (matches ref uniform)
            parr[o][u] = p;
            ps += p;
        }
        #pragma unroll
        for (int off = 32; off > 0; off >>= 1) ps += __shfl_down(ps, off, 64);
        __syncthreads();
        if ((tid & 63) == 0) red[tid >> 6] = ps;
        __syncthreads();
        ps = red[0] + red[1] + red[2] + red[3];
        float inv = 1.0f / ps;
        float4 st = make_float4(parr[o][0] * inv, parr[o][1] * inv, parr[o][2] * inv, parr[o][3] * inv);
        parr[o][0] = st.x; parr[o][1] = st.y; parr[o][2] = st.z; parr[o][3] = st.w;
        // post_softmax_attn output: [bs][h][i][j], bs*NH+h == b*16+o
        *(float4*)(attn_out + (((size_t)(b * 16 + o)) * NSEQ + i) * NSEQ + j0) = st;
    }

    // post talking-heads: attn2[o] = sum_c wpost[o][c] * parr[c]
    #pragma unroll
    for (int o = 0; o < 16; ++o) {
        float a0 = 0.f, a1 = 0.f, a2 = 0.f, a3 = 0.f;
        #pragma unroll
        for (int c = 0; c < 16; ++c) {
            float w = wpost[o * 16 + c];
            a0 = fmaf(w, parr[c][0], a0);
            a1 = fmaf(w, parr[c][1], a1);
            a2 = fmaf(w, parr[c][2], a2);
            a3 = fmaf(w, parr[c][3], a3);
        }
        *(float4*)(attn2 + (((size_t)(b * 16 + o)) * NSEQ + i) * NSEQ + j0) = make_float4(a0, a1, a2, a3);
    }
}

// ============================================================
// K5: out = attn2 @ v, gated, written as [bs][n][h*64+d]
// NN GEMM per bh: M=1024, N=64, K=1024. grid (16,1,32)
// ============================================================
__global__ __launch_bounds__(256) void k_av_gemm(
    const float* __restrict__ attn2, const float* __restrict__ v,
    const float* __restrict__ gates, float* __restrict__ gated)
{
    int bh = blockIdx.z;
    int bs = bh >> 3, h = bh & 7;
    const float* A = attn2 + (size_t)bh * NSEQ * NSEQ;
    const float* B = v + (size_t)bh * NSEQ * DH;
    __shared__ float As[16][68];
    __shared__ float Bs[16][68];
    int tid = threadIdx.x;
    int tx = tid & 15, ty = tid >> 4;
    int i0 = blockIdx.x * 64;
    int lr = tid >> 2;
    int lc = (tid & 3) << 2;
    int br = tid >> 4;          // 0..15
    int bc = (tid & 15) << 2;   // 0..60
    float acc[4][4] = {};
    for (int k0 = 0; k0 < NSEQ; k0 += 16) {
        float4 a = *(const float4*)(A + (size_t)(i0 + lr) * NSEQ + k0 + lc);
        As[lc + 0][lr] = a.x; As[lc + 1][lr] = a.y; As[lc + 2][lr] = a.z; As[lc + 3][lr] = a.w;
        float4 bb = *(const float4*)(B + (size_t)(k0 + br) * DH + bc);
        *(float4*)&Bs[br][bc] = bb;
        __syncthreads();
        #pragma unroll
        for (int kk = 0; kk < 16; ++kk) {
            float4 av = *(const float4*)&As[kk][ty << 2];
            float4 bv = *(const float4*)&Bs[kk][tx << 2];
            float aa[4] = {av.x, av.y, av.z, av.w};
            float bv4[4] = {bv.x, bv.y, bv.z, bv.w};
            #pragma unroll
            for (int e = 0; e < 4; ++e)
                #pragma unroll
                for (int f = 0; f < 4; ++f)
                    acc[e][f] = fmaf(aa[e], bv4[f], acc[e][f]);
        }
        __syncthreads();
    }
    #pragma unroll
    for (int e = 0; e < 4; ++e) {
        int i = i0 + (ty << 2) + e;
        float g = gates[((size_t)bs * NSEQ + i) * NH + h];
        float4 st = make_float4(acc[e][0] * g, acc[e][1] * g, acc[e][2] * g, acc[e][3] * g);
        *(float4*)(gated + ((size_t)bs * NSEQ + i) * DIM + h * DH + (tx << 2)) = st;
    }
}

// ============================================================
// K6: final projection out[4096 x 512] = gated @ wout^T (NT)
// ============================================================
__global__ __launch_bounds__(256) void k_out_gemm(
    const float* __restrict__ gated, const float* __restrict__ wout,
    float* __restrict__ out)
{
    __shared__ float As[16][68];
    __shared__ float Bs[16][68];
    int tid = threadIdx.x;
    int tx = tid & 15, ty = tid >> 4;
    int m0 = blockIdx.y * 64;
    int n0 = blockIdx.x * 64;
    int lr = tid >> 2;
    int lc = (tid & 3) << 2;
    float acc[4][4] = {};
    for (int k0 = 0; k0 < DIM; k0 += 16) {
        float4 a = *(const float4*)(gated + (size_t)(m0 + lr) * DIM + k0 + lc);
        float4 b = *(const float4*)(wout + (size_t)(n0 + lr) * DIM + k0 + lc);
        As[lc + 0][lr] = a.x; As[lc + 1][lr] = a.y; As[lc + 2][lr] = a.z; As[lc + 3][lr] = a.w;
        Bs[lc + 0][lr] = b.x; Bs[lc + 1][lr] = b.y; Bs[lc + 2][lr] = b.z; Bs[lc + 3][lr] = b.w;
        __syncthreads();
        #pragma unroll
        for (int kk = 0; kk < 16; ++kk) {
            float4 av = *(const float4*)&As[kk][ty << 2];
            float4 bv = *(const float4*)&Bs[kk][tx << 2];
            float aa[4] = {av.x, av.y, av.z, av.w};
            float bb[4] = {bv.x, bv.y, bv.z, bv.w};
            #pragma unroll
            for (int e = 0; e < 4; ++e)
                #pragma unroll
                for (int f = 0; f < 4; ++f)
                    acc[e][f] = fmaf(aa[e], bb[f], acc[e][f]);
        }
        __syncthreads();
    }
    #pragma unroll
    for (int e = 0; e < 4; ++e) {
        float4 st = make_float4(acc[e][0], acc[e][1], acc[e][2], acc[e][3]);
        *(float4*)(out + (size_t)(m0 + (ty << 2) + e) * DIM + n0 + (tx << 2)) = st;
    }
}

// ============================================================
extern "C" void kernel_launch(void* const* d_in, const int* in_sizes, int n_in,
                              void* d_out, int out_size, void* d_ws, size_t ws_size,
                              hipStream_t stream)
{
    (void)in_sizes; (void)n_in; (void)out_size; (void)ws_size;

    const float* x     = (const float*)d_in[0];
    const int*   mask  = (const int*)  d_in[1];   // bool -> int32 per harness convention
    const float* gamma = (const float*)d_in[2];
    const float* wqkv  = (const float*)d_in[3];
    const float* wg    = (const float*)d_in[4];
    const float* bg    = (const float*)d_in[5];
    const float* wpre  = (const float*)d_in[6];
    const float* wpost = (const float*)d_in[7];
    const float* wout  = (const float*)d_in[8];

    float* out      = (float*)d_out;
    float* attn_out = out + (size_t)BS4 * NSEQ * DIM;   // output 1: [4][8][1024][1024]

    float* ws    = (float*)d_ws;
    float* xn    = ws;                                   // 2,097,152 fl (reused as `gated` later)
    float* q     = ws + (size_t)2097152;                 // 2,097,152 fl
    float* kbuf  = ws + (size_t)2 * 2097152;             // 2,097,152 fl
    float* vbuf  = ws + (size_t)3 * 2097152;             // 2,097,152 fl
    float* gates = ws + (size_t)4 * 2097152;             //    32,768 fl
    float* sim   = ws + (size_t)4 * 2097152 + 32768;     // 33,554,432 fl (reused as attn2 in-place)

    k_rmsnorm_gates<<<dim3(BS4 * NSEQ), dim3(256), 0, stream>>>(x, gamma, wg, bg, xn, gates);
    k_qkv_gemm<<<dim3(24, 64), dim3(256), 0, stream>>>(xn, wqkv, q, kbuf, vbuf);
    k_qk<<<dim3(16, 16, 32), dim3(256), 0, stream>>>(q, kbuf, sim);
    k_talk_softmax<<<dim3(NSEQ, B2), dim3(256), 0, stream>>>(sim, mask, wpre, wpost, attn_out, sim);
    k_av_gemm<<<dim3(16, 1, 32), dim3(256), 0, stream>>>(sim, vbuf, gates, xn);
    k_out_gemm<<<dim3(8, 64), dim3(256), 0, stream>>>(xn, wout, out);
}

// Round 2
// 411.783 us; speedup vs baseline: 1.2783x; 1.2783x over previous
//
#include <hip/hip_runtime.h>
#include <cfloat>
#include <math.h>

#define B2   2
#define BS4  4
#define NH   8
#define DH   64
#define DIM  512
#define NSEQ 1024
#define AH   16

typedef __attribute__((ext_vector_type(8))) short short8;
typedef __attribute__((ext_vector_type(4))) float floatx4;

// ---------- bf16 helpers ----------
__device__ inline unsigned short f2bf(float x) {
    unsigned int u = __float_as_uint(x);
    unsigned int r = (u + 0x7fffu + ((u >> 16) & 1u)) >> 16;
    return (unsigned short)r;
}
__device__ inline float bf2f(unsigned short h) {
    return __uint_as_float(((unsigned int)h) << 16);
}
__device__ inline void split2(float x, unsigned short& h, unsigned short& l) {
    h = f2bf(x);
    l = f2bf(x - bf2f(h));
}

// ============================================================
// NT MFMA core: C[M,N] += A[M,K] * B[N,K]^T, bf16 frags.
// SPLIT=true: A,B given as hi/lo pairs, 3 MFMAs (≈fp32 precision).
// Wave tile = (MT*16) x (NT_*16). No LDS: direct b128 global loads.
// A-frag: m = lane&15, k = quad*8+j (contiguous 16B).
// ============================================================
template<int MT, int NT_, bool SPLIT>
__device__ inline void mfma_nt_core(
    const unsigned short* __restrict__ Ah, const unsigned short* __restrict__ Al,
    const unsigned short* __restrict__ Bh, const unsigned short* __restrict__ Bl,
    int K, int lda, int ldb, int arow, int bcol, floatx4 acc[MT][NT_])
{
    int lane = threadIdx.x & 63;
    int lr = lane & 15, lq = lane >> 4;
    for (int k0 = 0; k0 < K; k0 += 32) {
        short8 ah[MT], al[MT], bh[NT_], bl[NT_];
        #pragma unroll
        for (int mi = 0; mi < MT; ++mi) {
            size_t off = (size_t)(arow + mi * 16 + lr) * lda + k0 + lq * 8;
            ah[mi] = *(const short8*)(Ah + off);
            if (SPLIT) al[mi] = *(const short8*)(Al + off);
        }
        #pragma unroll
        for (int ni = 0; ni < NT_; ++ni) {
            size_t off = (size_t)(bcol + ni * 16 + lr) * ldb + k0 + lq * 8;
            bh[ni] = *(const short8*)(Bh + off);
            if (SPLIT) bl[ni] = *(const short8*)(Bl + off);
        }
        #pragma unroll
        for (int mi = 0; mi < MT; ++mi)
            #pragma unroll
            for (int ni = 0; ni < NT_; ++ni) {
                acc[mi][ni] = __builtin_amdgcn_mfma_f32_16x16x32_bf16(ah[mi], bh[ni], acc[mi][ni], 0, 0, 0);
                if (SPLIT) {
                    acc[mi][ni] = __builtin_amdgcn_mfma_f32_16x16x32_bf16(ah[mi], bl[ni], acc[mi][ni], 0, 0, 0);
                    acc[mi][ni] = __builtin_amdgcn_mfma_f32_16x16x32_bf16(al[mi], bh[ni], acc[mi][ni], 0, 0, 0);
                }
            }
    }
}

// ============================================================
// K1: RMSNorm + sigmoid gates; emits xn as bf16 hi/lo pairs.
// ============================================================
__global__ __launch_bounds__(256) void k_rmsnorm_gates(
    const float* __restrict__ x, const float* __restrict__ gamma,
    const float* __restrict__ wg, const float* __restrict__ bg,
    unsigned short* __restrict__ xn_h, unsigned short* __restrict__ xn_l,
    float* __restrict__ gates)
{
    int r = blockIdx.x;
    int tid = threadIdx.x;
    const float* xr = x + (size_t)r * DIM;
    float v0 = xr[tid];
    float v1 = xr[tid + 256];
    float ss = v0 * v0 + v1 * v1;
    #pragma unroll
    for (int off = 32; off > 0; off >>= 1) ss += __shfl_down(ss, off, 64);
    __shared__ float sc[4];
    __shared__ float scw[NH][4];
    if ((tid & 63) == 0) sc[tid >> 6] = ss;
    __syncthreads();
    float tot = sc[0] + sc[1] + sc[2] + sc[3];
    float rs = rsqrtf(tot * (1.0f / DIM) + 1e-5f);
    float n0 = v0 * rs * gamma[tid];
    float n1 = v1 * rs * gamma[tid + 256];
    unsigned short hh, ll;
    split2(n0, hh, ll);
    xn_h[(size_t)r * DIM + tid] = hh; xn_l[(size_t)r * DIM + tid] = ll;
    split2(n1, hh, ll);
    xn_h[(size_t)r * DIM + tid + 256] = hh; xn_l[(size_t)r * DIM + tid + 256] = ll;
    #pragma unroll
    for (int h = 0; h < NH; ++h) {
        float p = n0 * wg[h * DIM + tid] + n1 * wg[h * DIM + tid + 256];
        #pragma unroll
        for (int off = 32; off > 0; off >>= 1) p += __shfl_down(p, off, 64);
        if ((tid & 63) == 0) scw[h][tid >> 6] = p;
    }
    __syncthreads();
    if (tid < NH) {
        float g = scw[tid][0] + scw[tid][1] + scw[tid][2] + scw[tid][3] + bg[tid];
        gates[(size_t)r * NH + tid] = 1.0f / (1.0f + __expf(-g));
    }
}

// ============================================================
// Conversion kernels for weights
// ============================================================
__global__ __launch_bounds__(256) void k_cvt_split(
    const float* __restrict__ s, unsigned short* __restrict__ h,
    unsigned short* __restrict__ l, int n)
{
    for (int i = blockIdx.x * 256 + threadIdx.x; i < n; i += gridDim.x * 256) {
        unsigned short hh, ll;
        split2(s[i], hh, ll);
        h[i] = hh; l[i] = ll;
    }
}
__global__ __launch_bounds__(256) void k_cvt_plain(
    const float* __restrict__ s, unsigned short* __restrict__ h, int n)
{
    for (int i = blockIdx.x * 256 + threadIdx.x; i < n; i += gridDim.x * 256)
        h[i] = f2bf(s[i]);
}

// ============================================================
// K2: QKV projection, split-bf16 MFMA. C[4096x1536]=xn*wqkv^T
// block tile 128x64 (4 waves of 64x32). Scatter epilogue:
// q(x8)->q_h/l, k->k_h/l, v->vT_b transposed [bh][d][n].
// ============================================================
__global__ __launch_bounds__(256) void k_qkv_mfma(
    const unsigned short* __restrict__ xn_h, const unsigned short* __restrict__ xn_l,
    const unsigned short* __restrict__ wq_h, const unsigned short* __restrict__ wq_l,
    unsigned short* __restrict__ q_h, unsigned short* __restrict__ q_l,
    unsigned short* __restrict__ k_h, unsigned short* __restrict__ k_l,
    unsigned short* __restrict__ vT_b)
{
    int w = threadIdx.x >> 6;
    int am = blockIdx.y * 128 + (w & 1) * 64;
    int bn = blockIdx.x * 64 + (w >> 1) * 32;
    floatx4 acc[4][2];
    #pragma unroll
    for (int mi = 0; mi < 4; ++mi)
        #pragma unroll
        for (int ni = 0; ni < 2; ++ni) acc[mi][ni] = (floatx4){0.f, 0.f, 0.f, 0.f};
    mfma_nt_core<4, 2, true>(xn_h, xn_l, wq_h, wq_l, DIM, DIM, DIM, am, bn, acc);
    int lane = threadIdx.x & 63, lr = lane & 15, lq = lane >> 4;
    #pragma unroll
    for (int mi = 0; mi < 4; ++mi)
        #pragma unroll
        for (int ni = 0; ni < 2; ++ni)
            #pragma unroll
            for (int r = 0; r < 4; ++r) {
                int row = am + mi * 16 + lq * 4 + r;
                int col = bn + ni * 16 + lr;
                float v = acc[mi][ni][r];
                int bs = row >> 10, npos = row & 1023;
                int which = col >> 9, h = (col >> 6) & 7, d = col & 63;
                int bh = bs * 8 + h;
                if (which == 0) {
                    v *= 8.0f;  // q * sqrt(dim_head)
                    size_t idx = ((size_t)bh * NSEQ + npos) * DH + d;
                    unsigned short hh, ll; split2(v, hh, ll);
                    q_h[idx] = hh; q_l[idx] = ll;
                } else if (which == 1) {
                    size_t idx = ((size_t)bh * NSEQ + npos) * DH + d;
                    unsigned short hh, ll; split2(v, hh, ll);
                    k_h[idx] = hh; k_l[idx] = ll;
                } else {
                    vT_b[((size_t)bh * DH + d) * NSEQ + npos] = f2bf(v);
                }
            }
}

// ============================================================
// K3: sim = q*k^T per bh, split-bf16 MFMA. Writes logits DIRECTLY
// into d_out's attn region ([b*16+c] flat == [bs][h] flat).
// block tile 128(i) x 64(j).
// ============================================================
__global__ __launch_bounds__(256) void k_qk_mfma(
    const unsigned short* __restrict__ q_h, const unsigned short* __restrict__ q_l,
    const unsigned short* __restrict__ k_h, const unsigned short* __restrict__ k_l,
    float* __restrict__ simio)
{
    int bh = blockIdx.z;
    int w = threadIdx.x >> 6;
    int am = blockIdx.y * 128 + (w & 1) * 64;
    int bn = blockIdx.x * 64 + (w >> 1) * 32;
    const unsigned short* Ah = q_h + (size_t)bh * NSEQ * DH;
    const unsigned short* Al = q_l + (size_t)bh * NSEQ * DH;
    const unsigned short* Bh = k_h + (size_t)bh * NSEQ * DH;
    const unsigned short* Bl = k_l + (size_t)bh * NSEQ * DH;
    floatx4 acc[4][2];
    #pragma unroll
    for (int mi = 0; mi < 4; ++mi)
        #pragma unroll
        for (int ni = 0; ni < 2; ++ni) acc[mi][ni] = (floatx4){0.f, 0.f, 0.f, 0.f};
    mfma_nt_core<4, 2, true>(Ah, Al, Bh, Bl, DH, DH, DH, am, bn, acc);
    float* C = simio + ((size_t)bh << 20);
    int lane = threadIdx.x & 63, lr = lane & 15, lq = lane >> 4;
    #pragma unroll
    for (int mi = 0; mi < 4; ++mi)
        #pragma unroll
        for (int ni = 0; ni < 2; ++ni)
            #pragma unroll
            for (int r = 0; r < 4; ++r) {
                int row = am + mi * 16 + lq * 4 + r;
                int col = bn + ni * 16 + lr;
                C[(size_t)row * NSEQ + col] = acc[mi][ni][r];
            }
}

// ============================================================
// K4: pre-talk + mask + causal + softmax (IN PLACE over simio,
// which is d_out's attn region) + post-talk -> attn2 bf16.
// Block per (b,i); each thread owns 4 j across 16 channels.
// ============================================================
__global__ __launch_bounds__(256) void k_talk_softmax(
    float* __restrict__ simio, const int* __restrict__ mask,
    const float* __restrict__ wpre, const float* __restrict__ wpost,
    unsigned short* __restrict__ attn2_b)
{
    int i = blockIdx.x;
    int b = blockIdx.y;
    int tid = threadIdx.x;
    int j0 = tid << 2;

    float reg[16][4];
    #pragma unroll
    for (int c = 0; c < 16; ++c) {
        float4 t = *(const float4*)(simio + (((size_t)(b * 16 + c)) * NSEQ + i) * NSEQ + j0);
        reg[c][0] = t.x; reg[c][1] = t.y; reg[c][2] = t.z; reg[c][3] = t.w;
    }
    bool mb[2][4];
    #pragma unroll
    for (int s = 0; s < 2; ++s)
        #pragma unroll
        for (int u = 0; u < 4; ++u)
            mb[s][u] = (mask[(size_t)(b * 2 + s) * NSEQ + j0 + u] != 0) && ((j0 + u) <= i);

    __shared__ float red[4];
    float parr[16][4];

    #pragma unroll
    for (int o = 0; o < 16; ++o) {
        int s = o >> 3;
        float val[4];
        #pragma unroll
        for (int u = 0; u < 4; ++u) {
            float a = 0.0f;
            #pragma unroll
            for (int c = 0; c < 16; ++c) a = fmaf(wpre[o * 16 + c], reg[c][u], a);
            val[u] = mb[s][u] ? a : -FLT_MAX;
        }
        float mx = fmaxf(fmaxf(val[0], val[1]), fmaxf(val[2], val[3]));
        #pragma unroll
        for (int off = 32; off > 0; off >>= 1) mx = fmaxf(mx, __shfl_down(mx, off, 64));
        __syncthreads();
        if ((tid & 63) == 0) red[tid >> 6] = mx;
        __syncthreads();
        mx = fmaxf(fmaxf(red[0], red[1]), fmaxf(red[2], red[3]));
        float ps = 0.0f;
        #pragma unroll
        for (int u = 0; u < 4; ++u) {
            float p = __expf(val[u] - mx);
            parr[o][u] = p;
            ps += p;
        }
        #pragma unroll
        for (int off = 32; off > 0; off >>= 1) ps += __shfl_down(ps, off, 64);
        __syncthreads();
        if ((tid & 63) == 0) red[tid >> 6] = ps;
        __syncthreads();
        ps = red[0] + red[1] + red[2] + red[3];
        float inv = 1.0f / ps;
        float4 st = make_float4(parr[o][0] * inv, parr[o][1] * inv, parr[o][2] * inv, parr[o][3] * inv);
        parr[o][0] = st.x; parr[o][1] = st.y; parr[o][2] = st.z; parr[o][3] = st.w;
        // overwrite logits with post-softmax probs (output 1), in place
        *(float4*)(simio + (((size_t)(b * 16 + o)) * NSEQ + i) * NSEQ + j0) = st;
    }

    // post talking-heads -> bf16 attn2
    #pragma unroll
    for (int o = 0; o < 16; ++o) {
        float a0 = 0.f, a1 = 0.f, a2 = 0.f, a3 = 0.f;
        #pragma unroll
        for (int c = 0; c < 16; ++c) {
            float w = wpost[o * 16 + c];
            a0 = fmaf(w, parr[c][0], a0);
            a1 = fmaf(w, parr[c][1], a1);
            a2 = fmaf(w, parr[c][2], a2);
            a3 = fmaf(w, parr[c][3], a3);
        }
        unsigned long long pk = (unsigned long long)f2bf(a0)
                              | ((unsigned long long)f2bf(a1) << 16)
                              | ((unsigned long long)f2bf(a2) << 32)
                              | ((unsigned long long)f2bf(a3) << 48);
        *(unsigned long long*)(attn2_b + (((size_t)(b * 16 + o)) * NSEQ + i) * NSEQ + j0) = pk;
    }
}

// ============================================================
// K5: gated = (attn2 @ v) * gate, plain bf16 MFMA (NT with vT).
// block tile 64(i) x 64(d), 4 waves of 32x32. grid (16, 32).
// ============================================================
__global__ __launch_bounds__(256) void k_av_mfma(
    const unsigned short* __restrict__ attn2_b, const unsigned short* __restrict__ vT_b,
    const float* __restrict__ gates, unsigned short* __restrict__ gated_b)
{
    int bh = blockIdx.y;
    int bs = bh >> 3, h = bh & 7;
    int w = threadIdx.x >> 6;
    int am = blockIdx.x * 64 + (w & 1) * 32;
    int bn = (w >> 1) * 32;
    const unsigned short* Ah = attn2_b + ((size_t)bh << 20);
    const unsigned short* Bh = vT_b + (size_t)bh * DH * NSEQ;
    floatx4 acc[2][2];
    #pragma unroll
    for (int mi = 0; mi < 2; ++mi)
        #pragma unroll
        for (int ni = 0; ni < 2; ++ni) acc[mi][ni] = (floatx4){0.f, 0.f, 0.f, 0.f};
    mfma_nt_core<2, 2, false>(Ah, nullptr, Bh, nullptr, NSEQ, NSEQ, NSEQ, am, bn, acc);
    int lane = threadIdx.x & 63, lr = lane & 15, lq = lane >> 4;
    #pragma unroll
    for (int mi = 0; mi < 2; ++mi)
        #pragma unroll
        for (int ni = 0; ni < 2; ++ni)
            #pragma unroll
            for (int r = 0; r < 4; ++r) {
                int i = am + mi * 16 + lq * 4 + r;
                int d = bn + ni * 16 + lr;
                float g = gates[((size_t)bs * NSEQ + i) * NH + h];
                gated_b[((size_t)bs * NSEQ + i) * DIM + h * DH + d] = f2bf(acc[mi][ni][r] * g);
            }
}

// ============================================================
// K6: out = gated @ wout^T, plain bf16 MFMA. block 64x64. grid (8,64)
// ============================================================
__global__ __launch_bounds__(256) void k_out_mfma(
    const unsigned short* __restrict__ gated_b, const unsigned short* __restrict__ wout_b,
    float* __restrict__ out)
{
    int w = threadIdx.x >> 6;
    int am = blockIdx.y * 64 + (w & 1) * 32;
    int bn = blockIdx.x * 64 + (w >> 1) * 32;
    floatx4 acc[2][2];
    #pragma unroll
    for (int mi = 0; mi < 2; ++mi)
        #pragma unroll
        for (int ni = 0; ni < 2; ++ni) acc[mi][ni] = (floatx4){0.f, 0.f, 0.f, 0.f};
    mfma_nt_core<2, 2, false>(gated_b, nullptr, wout_b, nullptr, DIM, DIM, DIM, am, bn, acc);
    int lane = threadIdx.x & 63, lr = lane & 15, lq = lane >> 4;
    #pragma unroll
    for (int mi = 0; mi < 2; ++mi)
        #pragma unroll
        for (int ni = 0; ni < 2; ++ni)
            #pragma unroll
            for (int r = 0; r < 4; ++r) {
                int row = am + mi * 16 + lq * 4 + r;
                int col = bn + ni * 16 + lr;
                out[(size_t)row * DIM + col] = acc[mi][ni][r];
            }
}

// ============================================================
extern "C" void kernel_launch(void* const* d_in, const int* in_sizes, int n_in,
                              void* d_out, int out_size, void* d_ws, size_t ws_size,
                              hipStream_t stream)
{
    (void)in_sizes; (void)n_in; (void)out_size; (void)ws_size;

    const float* x     = (const float*)d_in[0];
    const int*   mask  = (const int*)  d_in[1];
    const float* gamma = (const float*)d_in[2];
    const float* wqkv  = (const float*)d_in[3];
    const float* wg    = (const float*)d_in[4];
    const float* bg    = (const float*)d_in[5];
    const float* wpre  = (const float*)d_in[6];
    const float* wpost = (const float*)d_in[7];
    const float* wout  = (const float*)d_in[8];

    float* out      = (float*)d_out;
    float* attn_out = out + (size_t)BS4 * NSEQ * DIM;  // sim lives here, softmaxed in place

    // workspace layout (bytes)
    char* ws = (char*)d_ws;
    unsigned short* xn_h    = (unsigned short*)(ws);                 //  4 MB
    unsigned short* xn_l    = (unsigned short*)(ws + 4194304);       //  4 MB
    unsigned short* wq_h    = (unsigned short*)(ws + 8388608);       //  1.5 MB
    unsigned short* wq_l    = (unsigned short*)(ws + 9961472);       //  1.5 MB
    unsigned short* wout_b  = (unsigned short*)(ws + 11534336);      //  0.5 MB
    float*          gates   = (float*)         (ws + 12058624);      //  128 KB
    unsigned short* q_h     = (unsigned short*)(ws + 12189696);      //  4 MB
    unsigned short* q_l     = (unsigned short*)(ws + 16384000);      //  4 MB
    unsigned short* k_h     = (unsigned short*)(ws + 20578304);      //  4 MB
    unsigned short* k_l     = (unsigned short*)(ws + 24772608);      //  4 MB
    unsigned short* vT_b    = (unsigned short*)(ws + 28966912);      //  4 MB
    unsigned short* gated_b = (unsigned short*)(ws + 33161216);      //  4 MB
    unsigned short* attn2_b = (unsigned short*)(ws + 37355520);      // 64 MB
    // total ~104.5 MB

    k_rmsnorm_gates<<<dim3(BS4 * NSEQ), dim3(256), 0, stream>>>(x, gamma, wg, bg, xn_h, xn_l, gates);
    k_cvt_split<<<dim3(768), dim3(256), 0, stream>>>(wqkv, wq_h, wq_l, 3 * DIM * NH * DH);
    k_cvt_plain<<<dim3(256), dim3(256), 0, stream>>>(wout, wout_b, DIM * NH * DH);
    k_qkv_mfma<<<dim3(24, 32), dim3(256), 0, stream>>>(xn_h, xn_l, wq_h, wq_l, q_h, q_l, k_h, k_l, vT_b);
    k_qk_mfma<<<dim3(16, 8, 32), dim3(256), 0, stream>>>(q_h, q_l, k_h, k_l, attn_out);
    k_talk_softmax<<<dim3(NSEQ, B2), dim3(256), 0, stream>>>(attn_out, mask, wpre, wpost, attn2_b);
    k_av_mfma<<<dim3(16, 32), dim3(256), 0, stream>>>(attn2_b, vT_b, gates, gated_b);
    k_out_mfma<<<dim3(8, 64), dim3(256), 0, stream>>>(gated_b, wout_b, out);
}